// Round 1
// baseline (859.490 us; speedup 1.0000x reference)
//
#include <hip/hip_runtime.h>
#include <hip/hip_bf16.h>
#include <stdint.h>

// EncoderLayer on MI355X: bf16 MFMA GEMMs + fp32 softmax/LN epilogues.
// Pipeline: prep(convert/transpose) -> QKV -> Vt -> scores -> softmax ->
//           context -> Wo+resid -> LN1 -> FFN1(relu) -> FFN2+resid -> LN2.

using bf16_t  = __hip_bfloat16;
using short8  = __attribute__((ext_vector_type(8))) short;
using short4v = __attribute__((ext_vector_type(4))) short;
using f32x4   = __attribute__((ext_vector_type(4))) float;

#define DEV static __device__ __forceinline__

DEV short bfbits(float f) {
  bf16_t h = __float2bfloat16(f);
  union { bf16_t h; short s; } u; u.h = h; return u.s;
}

// ---------------- elementwise fp32 -> bf16 (4 elems/thread) ----------------
__global__ __launch_bounds__(256) void k_f32_to_bf16(const float* __restrict__ in,
                                                     bf16_t* __restrict__ out) {
  size_t i = ((size_t)blockIdx.x * 256 + threadIdx.x) * 4;
  f32x4 x = *(const f32x4*)(in + i);
  short4v o;
  o[0] = bfbits(x[0]); o[1] = bfbits(x[1]); o[2] = bfbits(x[2]); o[3] = bfbits(x[3]);
  *(short4v*)((short*)out + i) = o;
}

// ---------------- transpose fp32 [R][C] -> bf16 [C][R] ----------------
__global__ __launch_bounds__(256) void k_transpose_f32_bf16(const float* __restrict__ in,
                                                            bf16_t* __restrict__ out,
                                                            int R, int C) {
  __shared__ float tile[32][33];
  int tx = threadIdx.x & 31, ty = threadIdx.x >> 5;   // 32 x 8
  int r0 = blockIdx.y * 32, c0 = blockIdx.x * 32;
  #pragma unroll
  for (int i = 0; i < 4; ++i)
    tile[ty + i * 8][tx] = in[(size_t)(r0 + ty + i * 8) * C + c0 + tx];
  __syncthreads();
  #pragma unroll
  for (int i = 0; i < 4; ++i)
    out[(size_t)(c0 + ty + i * 8) * R + r0 + tx] = __float2bfloat16(tile[tx][ty + i * 8]);
}

// ---------------- batched transpose bf16 [R][C] -> [C][R] ----------------
__global__ __launch_bounds__(256) void k_transpose_bf16_b(const bf16_t* __restrict__ in,
                                                          bf16_t* __restrict__ out,
                                                          int R, int C, long sIn, long sOut) {
  __shared__ bf16_t tile[32][33];
  const bf16_t* inz = in + (size_t)blockIdx.z * sIn;
  bf16_t* outz = out + (size_t)blockIdx.z * sOut;
  int tx = threadIdx.x & 31, ty = threadIdx.x >> 5;
  int r0 = blockIdx.y * 32, c0 = blockIdx.x * 32;
  #pragma unroll
  for (int i = 0; i < 4; ++i)
    tile[ty + i * 8][tx] = inz[(size_t)(r0 + ty + i * 8) * C + c0 + tx];
  __syncthreads();
  #pragma unroll
  for (int i = 0; i < 4; ++i)
    outz[(size_t)(c0 + ty + i * 8) * R + r0 + tx] = tile[tx][ty + i * 8];
}

// ---------------- GEMM: C[M][N] = A[M][K](bf16 or f32) @ Bt[N][K](bf16) ----------------
// Block 256 thr = 4 waves (2x2), wave tile (BM/2)x(BN/2), MFMA 16x16x32 bf16.
// A-frag: A[m=lane&15][k=(lane>>4)*8+j]; B-frag symmetric on Bt; C/D: col=lane&15,
// row=(lane>>4)*4+reg  [verified layouts per cdna_hip_programming.md §3].
template<int BM, int BN, bool AF32, bool ALPHA, bool BIAS, bool RELU, bool RESID,
         bool OUTF, bool OUTB>
__global__ __launch_bounds__(256)
void k_gemm_bt(const void* __restrict__ Ap, const bf16_t* __restrict__ Btp,
               float* __restrict__ Cf, bf16_t* __restrict__ Cb,
               const float* __restrict__ bias, const float* __restrict__ resid,
               int Kdim, int lda, int ldb, int ldc, float alpha,
               long strA, long strB, long strC) {
  constexpr int BK = 32, LDSK = 40;  // +8 bf16 pad: 80B rows, 16B-aligned, conflict-lite
  constexpr int WTM = BM / 2, WTN = BN / 2;
  constexpr int MI = WTM / 16, NI = WTN / 16;
  __shared__ __align__(16) bf16_t sA[BM][LDSK];
  __shared__ __align__(16) bf16_t sB[BN][LDSK];

  const int tid = threadIdx.x;
  const int lane = tid & 63;
  const int wv = tid >> 6;
  const int wm = wv & 1, wn = wv >> 1;
  const int z = blockIdx.z;
  const size_t m0 = (size_t)blockIdx.y * BM;
  const size_t n0 = (size_t)blockIdx.x * BN;

  const bf16_t* A16 = AF32 ? nullptr : ((const bf16_t*)Ap + (size_t)z * strA);
  const float*  A32 = AF32 ? ((const float*)Ap + (size_t)z * strA) : nullptr;
  const bf16_t* Bp  = Btp + (size_t)z * strB;

  f32x4 acc[MI][NI] = {};

  const int srow = tid >> 2;         // 0..63
  const int skc  = (tid & 3) * 8;    // 0,8,16,24

  for (int k0 = 0; k0 < Kdim; k0 += BK) {
    #pragma unroll
    for (int j = 0; j < BM / 64; ++j) {
      int r = j * 64 + srow;
      if (AF32) {
        const float* p = A32 + (m0 + r) * (size_t)lda + k0 + skc;
        f32x4 f0 = *(const f32x4*)p;
        f32x4 f1 = *(const f32x4*)(p + 4);
        short8 v;
        v[0] = bfbits(f0[0]); v[1] = bfbits(f0[1]); v[2] = bfbits(f0[2]); v[3] = bfbits(f0[3]);
        v[4] = bfbits(f1[0]); v[5] = bfbits(f1[1]); v[6] = bfbits(f1[2]); v[7] = bfbits(f1[3]);
        *(short8*)(&sA[r][skc]) = v;
      } else {
        *(short8*)(&sA[r][skc]) =
            *(const short8*)(A16 + (m0 + r) * (size_t)lda + k0 + skc);
      }
    }
    #pragma unroll
    for (int j = 0; j < BN / 64; ++j) {
      int r = j * 64 + srow;
      *(short8*)(&sB[r][skc]) =
          *(const short8*)(Bp + (n0 + r) * (size_t)ldb + k0 + skc);
    }
    __syncthreads();

    const int fm = wm * WTM + (lane & 15);
    const int fn = wn * WTN + (lane & 15);
    const int fk = (lane >> 4) * 8;
    short8 av[MI], bvv[NI];
    #pragma unroll
    for (int mi = 0; mi < MI; ++mi) av[mi] = *(const short8*)(&sA[fm + mi * 16][fk]);
    #pragma unroll
    for (int ni = 0; ni < NI; ++ni) bvv[ni] = *(const short8*)(&sB[fn + ni * 16][fk]);
    #pragma unroll
    for (int mi = 0; mi < MI; ++mi)
      #pragma unroll
      for (int ni = 0; ni < NI; ++ni)
        acc[mi][ni] = __builtin_amdgcn_mfma_f32_16x16x32_bf16(av[mi], bvv[ni],
                                                              acc[mi][ni], 0, 0, 0);
    __syncthreads();
  }

  const size_t cz = (size_t)z * strC;
  const int col0 = (int)n0 + wn * WTN + (lane & 15);
  const int row0 = (int)m0 + wm * WTM + ((lane >> 4) << 2);
  #pragma unroll
  for (int ni = 0; ni < NI; ++ni) {
    const int col = col0 + ni * 16;
    const float bval = BIAS ? bias[col] : 0.0f;
    #pragma unroll
    for (int mi = 0; mi < MI; ++mi) {
      #pragma unroll
      for (int r = 0; r < 4; ++r) {
        int row = row0 + mi * 16 + r;
        float v = acc[mi][ni][r];
        if (ALPHA) v *= alpha;
        v += bval;
        size_t off = cz + (size_t)row * ldc + col;
        if (RESID) v += resid[off];
        if (RELU) v = fmaxf(v, 0.0f);
        if (OUTF) Cf[off] = v;
        if (OUTB) Cb[off] = __float2bfloat16(v);
      }
    }
  }
}

// ---------------- row softmax, width 1024, in place ----------------
__global__ __launch_bounds__(256) void k_softmax(float* __restrict__ p) {
  float* r = p + (size_t)blockIdx.x * 1024;
  const int t = threadIdx.x;
  f32x4 x = *(const f32x4*)(r + t * 4);
  float m = fmaxf(fmaxf(x[0], x[1]), fmaxf(x[2], x[3]));
  #pragma unroll
  for (int o = 32; o > 0; o >>= 1) m = fmaxf(m, __shfl_xor(m, o, 64));
  __shared__ float sm[4], ssum[4];
  if ((t & 63) == 0) sm[t >> 6] = m;
  __syncthreads();
  m = fmaxf(fmaxf(sm[0], sm[1]), fmaxf(sm[2], sm[3]));
  f32x4 e;
  e[0] = __expf(x[0] - m); e[1] = __expf(x[1] - m);
  e[2] = __expf(x[2] - m); e[3] = __expf(x[3] - m);
  float s = e[0] + e[1] + e[2] + e[3];
  #pragma unroll
  for (int o = 32; o > 0; o >>= 1) s += __shfl_xor(s, o, 64);
  if ((t & 63) == 0) ssum[t >> 6] = s;
  __syncthreads();
  s = ssum[0] + ssum[1] + ssum[2] + ssum[3];
  float inv = 1.0f / s;
  e[0] *= inv; e[1] *= inv; e[2] *= inv; e[3] *= inv;
  *(f32x4*)(r + t * 4) = e;
}

// ---------------- row layernorm, width 1024, in place (+optional bf16 copy) -------
__global__ __launch_bounds__(256) void k_layernorm(float* __restrict__ io,
                                                   bf16_t* __restrict__ ob,
                                                   const float* __restrict__ g,
                                                   const float* __restrict__ bta) {
  float* r = io + (size_t)blockIdx.x * 1024;
  const int t = threadIdx.x;
  f32x4 x = *(const f32x4*)(r + t * 4);
  float s = x[0] + x[1] + x[2] + x[3];
  float s2 = x[0] * x[0] + x[1] * x[1] + x[2] * x[2] + x[3] * x[3];
  #pragma unroll
  for (int o = 32; o > 0; o >>= 1) { s += __shfl_xor(s, o, 64); s2 += __shfl_xor(s2, o, 64); }
  __shared__ float as[4], as2[4];
  if ((t & 63) == 0) { as[t >> 6] = s; as2[t >> 6] = s2; }
  __syncthreads();
  s = as[0] + as[1] + as[2] + as[3];
  s2 = as2[0] + as2[1] + as2[2] + as2[3];
  float mu = s * (1.0f / 1024.0f);
  float var = s2 * (1.0f / 1024.0f) - mu * mu;
  float rs = rsqrtf(var + 1e-5f);
  f32x4 gg = *(const f32x4*)(g + t * 4);
  f32x4 bb = *(const f32x4*)(bta + t * 4);
  f32x4 y;
  #pragma unroll
  for (int i = 0; i < 4; ++i) y[i] = (x[i] - mu) * rs * gg[i] + bb[i];
  *(f32x4*)(r + t * 4) = y;
  if (ob) {
    short4v o4;
    o4[0] = bfbits(y[0]); o4[1] = bfbits(y[1]); o4[2] = bfbits(y[2]); o4[3] = bfbits(y[3]);
    *(short4v*)((short*)ob + (size_t)blockIdx.x * 1024 + t * 4) = o4;
  }
}

extern "C" void kernel_launch(void* const* d_in, const int* in_sizes, int n_in,
                              void* d_out, int out_size, void* d_ws, size_t ws_size,
                              hipStream_t stream) {
  (void)in_sizes; (void)n_in; (void)out_size;
  const float* inputs = (const float*)d_in[0];
  const float* Wq = (const float*)d_in[1];  const float* bq = (const float*)d_in[2];
  const float* Wk = (const float*)d_in[3];  const float* bk = (const float*)d_in[4];
  const float* Wv = (const float*)d_in[5];  const float* bv = (const float*)d_in[6];
  const float* Wo = (const float*)d_in[7];  const float* bo = (const float*)d_in[8];
  const float* ln1g = (const float*)d_in[9];  const float* ln1b = (const float*)d_in[10];
  const float* W1 = (const float*)d_in[11]; const float* b1 = (const float*)d_in[12];
  const float* W2 = (const float*)d_in[13]; const float* b2 = (const float*)d_in[14];
  const float* ln2g = (const float*)d_in[15]; const float* ln2b = (const float*)d_in[16];

  const size_t MB = 1ull << 20;
  if (ws_size < 96 * MB) return;  // layout below needs 96 MB scratch

  char* ws = (char*)d_ws;
  bf16_t* WQT  = (bf16_t*)(ws + 0 * MB);   // [1024][1024]
  bf16_t* WKT  = (bf16_t*)(ws + 2 * MB);
  bf16_t* WVT  = (bf16_t*)(ws + 4 * MB);
  bf16_t* WOT  = (bf16_t*)(ws + 6 * MB);
  bf16_t* W1T  = (bf16_t*)(ws + 8 * MB);   // [4096][1024]
  bf16_t* W2T  = (bf16_t*)(ws + 16 * MB);  // [1024][4096]
  bf16_t* XB   = (bf16_t*)(ws + 24 * MB);  // [4096][1024]; dead after QKV
  bf16_t* QB   = (bf16_t*)(ws + 32 * MB);  // dead after scores
  bf16_t* KB   = (bf16_t*)(ws + 40 * MB);  // dead after scores
  bf16_t* VB   = (bf16_t*)(ws + 48 * MB);  // dead after Vt transpose
  bf16_t* VT   = (bf16_t*)(ws + 56 * MB);  // [64 batches][64][1024]; dead after ctx
  bf16_t* CTX  = (bf16_t*)(ws + 24 * MB);  // reuse XB slot
  float*  OUT1F = (float*)(ws + 40 * MB);  // fp32 [4096][1024] (reuse KB+VB slots)
  bf16_t* OUT1B = (bf16_t*)(ws + 32 * MB); // reuse QB slot
  bf16_t* HB   = (bf16_t*)(ws + 64 * MB);  // [4096][4096]

  float* outF = (float*)d_out;             // [4096][1024]
  float* attn = outF + 4194304;            // [64][1024][1024] fp32 (final output region)

  // --- prep: bf16 input copy + transposed bf16 weights ---
  k_f32_to_bf16<<<4096, 256, 0, stream>>>(inputs, XB);
  k_transpose_f32_bf16<<<dim3(32, 32), 256, 0, stream>>>(Wq, WQT, 1024, 1024);
  k_transpose_f32_bf16<<<dim3(32, 32), 256, 0, stream>>>(Wk, WKT, 1024, 1024);
  k_transpose_f32_bf16<<<dim3(32, 32), 256, 0, stream>>>(Wv, WVT, 1024, 1024);
  k_transpose_f32_bf16<<<dim3(32, 32), 256, 0, stream>>>(Wo, WOT, 1024, 1024);
  k_transpose_f32_bf16<<<dim3(128, 32), 256, 0, stream>>>(W1, W1T, 1024, 4096);
  k_transpose_f32_bf16<<<dim3(32, 128), 256, 0, stream>>>(W2, W2T, 4096, 1024);

  // --- QKV projections: [4096,1024] @ [1024,1024] ---
  k_gemm_bt<128, 128, false, false, true, false, false, false, true>
      <<<dim3(8, 32, 1), 256, 0, stream>>>(XB, WQT, nullptr, QB, bq, nullptr,
                                           1024, 1024, 1024, 1024, 1.0f, 0, 0, 0);
  k_gemm_bt<128, 128, false, false, true, false, false, false, true>
      <<<dim3(8, 32, 1), 256, 0, stream>>>(XB, WKT, nullptr, KB, bk, nullptr,
                                           1024, 1024, 1024, 1024, 1.0f, 0, 0, 0);
  k_gemm_bt<128, 128, false, false, true, false, false, false, true>
      <<<dim3(8, 32, 1), 256, 0, stream>>>(XB, WVT, nullptr, VB, bv, nullptr,
                                           1024, 1024, 1024, 1024, 1.0f, 0, 0, 0);

  // --- per-"head" V transpose: [1024][64] -> [64][1024], 64 batches ---
  k_transpose_bf16_b<<<dim3(2, 32, 64), 256, 0, stream>>>(VB, VT, 1024, 64, 65536, 65536);

  // --- scores = q @ k^T * 1/8 -> attn region (fp32), batched over 64 ---
  k_gemm_bt<128, 128, false, true, false, false, false, true, false>
      <<<dim3(8, 8, 64), 256, 0, stream>>>(QB, KB, attn, nullptr, nullptr, nullptr,
                                           64, 64, 64, 1024, 0.125f, 65536, 65536, 1048576);

  // --- softmax rows, in place ---
  k_softmax<<<65536, 256, 0, stream>>>(attn);

  // --- context = attn(fp32->bf16) @ v, batched ---
  k_gemm_bt<128, 64, true, false, false, false, false, false, true>
      <<<dim3(1, 8, 64), 256, 0, stream>>>(attn, VT, nullptr, CTX, nullptr, nullptr,
                                           1024, 1024, 1024, 64, 1.0f, 1048576, 65536, 65536);

  // --- out-proj + bias + residual(inputs) -> OUT1F fp32 ---
  k_gemm_bt<128, 128, false, false, true, false, true, true, false>
      <<<dim3(8, 32, 1), 256, 0, stream>>>(CTX, WOT, OUT1F, nullptr, bo, inputs,
                                           1024, 1024, 1024, 1024, 1.0f, 0, 0, 0);

  // --- LN1 in place + bf16 copy ---
  k_layernorm<<<4096, 256, 0, stream>>>(OUT1F, OUT1B, ln1g, ln1b);

  // --- FFN1: relu(out1 @ W1 + b1) -> HB bf16 [4096][4096] ---
  k_gemm_bt<128, 128, false, false, true, true, false, false, true>
      <<<dim3(32, 32, 1), 256, 0, stream>>>(OUT1B, W1T, nullptr, HB, b1, nullptr,
                                            1024, 1024, 1024, 4096, 1.0f, 0, 0, 0);

  // --- FFN2: HB @ W2 + b2 + out1 -> d_out[0:4M] fp32 ---
  k_gemm_bt<128, 128, false, false, true, false, true, true, false>
      <<<dim3(8, 32, 1), 256, 0, stream>>>(HB, W2T, outF, nullptr, b2, OUT1F,
                                           4096, 4096, 4096, 1024, 1.0f, 0, 0, 0);

  // --- LN2 in place on d_out ---
  k_layernorm<<<4096, 256, 0, stream>>>(outF, nullptr, ln2g, ln2b);
}